// Round 1
// baseline (7669.127 us; speedup 1.0000x reference)
//
#include <hip/hip_runtime.h>

constexpr int LEN = 5265;
constexpr long NTOK = 8L * LEN;   // 42120
constexpr int DM = 256;

// ---------------------------------------------------------------- pack
__global__ __launch_bounds__(256) void pack_kernel(
    const float* __restrict__ s0, const float* __restrict__ s1,
    const float* __restrict__ s2, const float* __restrict__ s3,
    const float* __restrict__ p0, const float* __restrict__ p1,
    const float* __restrict__ p2, const float* __restrict__ p3,
    const float* __restrict__ lev,
    float* __restrict__ x, float* __restrict__ pos)
{
    long t = (long)blockIdx.x * 256 + threadIdx.x;
    if (t >= NTOK * 256) return;
    int c = (int)(t & 255);
    long r = t >> 8;
    int q = (int)(r % LEN);
    int B = (int)(r / LEN);
    int lvl, base, n;
    const float *sp, *pp;
    if (q < 4608)      { lvl = 0; base = 0;    n = 4608; sp = s0; pp = p0; }
    else if (q < 5184) { lvl = 1; base = 4608; n = 576;  sp = s1; pp = p1; }
    else if (q < 5256) { lvl = 2; base = 5184; n = 72;   sp = s2; pp = p2; }
    else               { lvl = 3; base = 5256; n = 9;    sp = s3; pp = p3; }
    int s = q - base;
    long si = ((long)B * 256 + c) * n + s;
    x[t] = sp[si];
    pos[t] = pp[si] + lev[lvl * 256 + c];
}

// ---------------------------------------------------------------- ref points
__global__ __launch_bounds__(64) void ref_kernel(float* __restrict__ refb)
{
    int q = blockIdx.x * 64 + threadIdx.x;
    if (q >= LEN) return;
    int base, D_, H_, W_;
    if (q < 4608)      { base = 0;    D_ = 8; H_ = 24; W_ = 24; }
    else if (q < 5184) { base = 4608; D_ = 4; H_ = 12; W_ = 12; }
    else if (q < 5256) { base = 5184; D_ = 2; H_ = 6;  W_ = 6;  }
    else               { base = 5256; D_ = 1; H_ = 3;  W_ = 3;  }
    int s = q - base;
    int hw = H_ * W_;
    int z = s / hw; int rem = s - z * hw;
    int y = rem / W_; int xx = rem - y * W_;
    refb[q * 3 + 0] = (xx + 0.5f) / (float)W_;
    refb[q * 3 + 1] = (y + 0.5f) / (float)H_;
    refb[q * 3 + 2] = (z + 0.5f) / (float)D_;
}

// ---------------------------------------------------------------- GEMM
// C[M,N] = (A (+A2)) @ W[K,N] + bias, optional relu.
// 128x128 tile, BK=8, 256 threads, 8x8 per thread.
template<bool ADD, bool RELU>
__global__ __launch_bounds__(256) void gemm_kernel(
    const float* __restrict__ A, const float* __restrict__ A2,
    const float* __restrict__ W, const float* __restrict__ bias,
    float* __restrict__ C, int M, int K, int N)
{
    __shared__ float lds_a[8][128];  // [k][m]
    __shared__ float lds_b[8][128];  // [k][n]
    const int tid = threadIdx.x;
    const int tx = tid & 15;         // 0..15 -> col group
    const int ty = tid >> 4;         // 0..15 -> row group
    const int row0 = blockIdx.x * 128;
    const int col0 = blockIdx.y * 128;

    const int arow = tid >> 1;            // 0..127
    const int ak   = (tid & 1) * 4;       // 0 or 4
    const int bk   = tid >> 5;            // 0..7
    const int bnn  = (tid & 31) * 4;      // 0..124

    float acc[8][8];
#pragma unroll
    for (int i = 0; i < 8; ++i)
#pragma unroll
        for (int j = 0; j < 8; ++j) acc[i][j] = 0.f;

    for (int k0 = 0; k0 < K; k0 += 8) {
        float4 av = make_float4(0.f, 0.f, 0.f, 0.f);
        const int ar = row0 + arow;
        if (ar < M) {
            av = *(const float4*)&A[(long)ar * K + k0 + ak];
            if (ADD) {
                const float4 a2 = *(const float4*)&A2[(long)ar * K + k0 + ak];
                av.x += a2.x; av.y += a2.y; av.z += a2.z; av.w += a2.w;
            }
        }
        const float4 bv = *(const float4*)&W[(long)(k0 + bk) * N + col0 + bnn];
        __syncthreads();
        lds_a[ak + 0][arow] = av.x;
        lds_a[ak + 1][arow] = av.y;
        lds_a[ak + 2][arow] = av.z;
        lds_a[ak + 3][arow] = av.w;
        *(float4*)&lds_b[bk][bnn] = bv;
        __syncthreads();
#pragma unroll
        for (int kk = 0; kk < 8; ++kk) {
            float4 a0 = *(const float4*)&lds_a[kk][ty * 8];
            float4 a1 = *(const float4*)&lds_a[kk][ty * 8 + 4];
            float4 b0 = *(const float4*)&lds_b[kk][tx * 8];
            float4 b1 = *(const float4*)&lds_b[kk][tx * 8 + 4];
            float am[8] = {a0.x, a0.y, a0.z, a0.w, a1.x, a1.y, a1.z, a1.w};
            float bm[8] = {b0.x, b0.y, b0.z, b0.w, b1.x, b1.y, b1.z, b1.w};
#pragma unroll
            for (int i = 0; i < 8; ++i)
#pragma unroll
                for (int j = 0; j < 8; ++j) acc[i][j] += am[i] * bm[j];
        }
    }

    const int cc = col0 + tx * 8;
    float bv8[8];
#pragma unroll
    for (int j = 0; j < 8; ++j) bv8[j] = bias[cc + j];
#pragma unroll
    for (int i = 0; i < 8; ++i) {
        const int row = row0 + ty * 8 + i;
        if (row < M) {
            float o[8];
#pragma unroll
            for (int j = 0; j < 8; ++j) {
                o[j] = acc[i][j] + bv8[j];
                if (RELU) o[j] = fmaxf(o[j], 0.f);
            }
            *(float4*)&C[(long)row * N + cc]     = make_float4(o[0], o[1], o[2], o[3]);
            *(float4*)&C[(long)row * N + cc + 4] = make_float4(o[4], o[5], o[6], o[7]);
        }
    }
}

// ---------------------------------------------------------------- MSDA sampling
// out[b,q,h,:] = sum over 16 points, 8 corners of w * value[b, base+idx, h, :]
__global__ __launch_bounds__(256) void msda_sample_kernel(
    const float* __restrict__ value,  // (B,LEN,8,32)
    const float* __restrict__ offb,   // (B,LEN,8,4,4,3)
    const float* __restrict__ attnl,  // (B,LEN,8,16)
    const float* __restrict__ refb,   // (LEN,3)
    float* __restrict__ out)          // (B,LEN,8,32)
{
    __shared__ float s_w[8][128];
    __shared__ int   s_i[8][128];
    const int tid = threadIdx.x;
    const long gid0 = (long)blockIdx.x * 8;

    if (tid < 128) {
        const int g = tid >> 4, pt = tid & 15;
        const long gg = gid0 + g;                 // (b*LEN+q)*8+h
        const int h = (int)(gg & 7);
        const long bq = gg >> 3;
        const int q = (int)(bq % LEN);
        const int b = (int)(bq / LEN);

        const float* lg = &attnl[bq * 128 + h * 16];
        float mx = lg[0];
#pragma unroll
        for (int j = 1; j < 16; ++j) mx = fmaxf(mx, lg[j]);
        float den = 0.f;
#pragma unroll
        for (int j = 0; j < 16; ++j) den += __expf(lg[j] - mx);
        const float aw = __expf(lg[pt] - mx) / den;

        const int lvl = pt >> 2;
        int D_, H_, W_, base;
        if (lvl == 0)      { D_ = 8; H_ = 24; W_ = 24; base = 0; }
        else if (lvl == 1) { D_ = 4; H_ = 12; W_ = 12; base = 4608; }
        else if (lvl == 2) { D_ = 2; H_ = 6;  W_ = 6;  base = 5184; }
        else               { D_ = 1; H_ = 3;  W_ = 3;  base = 5256; }
        const float fW = (float)W_, fH = (float)H_, fD = (float)D_;

        const float* op = &offb[(bq * 8 + h) * 48 + pt * 3];
        const float lx = refb[q * 3 + 0] + op[0] / fW;
        const float ly = refb[q * 3 + 1] + op[1] / fH;
        const float lz = refb[q * 3 + 2] + op[2] / fD;
        const float X = lx * fW - 0.5f, Y = ly * fH - 0.5f, Z = lz * fD - 0.5f;
        const float x0f = floorf(X), y0f = floorf(Y), z0f = floorf(Z);
        const float fx = X - x0f, fy = Y - y0f, fz = Z - z0f;
        const int x0 = (int)x0f, y0 = (int)y0f, z0 = (int)z0f;
#pragma unroll
        for (int c = 0; c < 8; ++c) {
            const int dx = c & 1, dy = (c >> 1) & 1, dz = c >> 2;
            const int xi = x0 + dx, yi = y0 + dy, zi = z0 + dz;
            float w = (dx ? fx : 1.f - fx) * (dy ? fy : 1.f - fy) * (dz ? fz : 1.f - fz);
            const bool valid = (xi >= 0) && (xi < W_) && (yi >= 0) && (yi < H_) &&
                               (zi >= 0) && (zi < D_);
            const int xc = min(max(xi, 0), W_ - 1);
            const int yc = min(max(yi, 0), H_ - 1);
            const int zc = min(max(zi, 0), D_ - 1);
            const int n = (zc * H_ + yc) * W_ + xc;
            const long vidx = ((long)b * LEN + base + n) * 8 + h;
            s_w[g][pt * 8 + c] = valid ? w * aw : 0.f;
            s_i[g][pt * 8 + c] = (int)vidx;
        }
    }
    __syncthreads();

    const int g = tid >> 5;
    const int d = tid & 31;
    const long gg = gid0 + g;
    float acc = 0.f;
#pragma unroll 4
    for (int i = 0; i < 128; ++i) {
        const float w = s_w[g][i];
        acc += w * value[(long)s_i[g][i] * 32 + d];
    }
    out[gg * 32 + d] = acc;
}

// ---------------------------------------------------------------- residual + LN
__global__ __launch_bounds__(256) void resid_ln_kernel(
    float* __restrict__ x, const float* __restrict__ r,
    const float* __restrict__ g, const float* __restrict__ be)
{
    const long tok = (long)blockIdx.x * 4 + (threadIdx.x >> 6);
    const int lane = threadIdx.x & 63;
    if (tok >= NTOK) return;
    const float4 xv = *(const float4*)&x[tok * 256 + lane * 4];
    const float4 rv = *(const float4*)&r[tok * 256 + lane * 4];
    float s0 = xv.x + rv.x, s1 = xv.y + rv.y, s2 = xv.z + rv.z, s3 = xv.w + rv.w;
    float sum = s0 + s1 + s2 + s3;
#pragma unroll
    for (int o = 32; o > 0; o >>= 1) sum += __shfl_xor(sum, o);
    const float mean = sum * (1.f / 256.f);
    const float d0 = s0 - mean, d1 = s1 - mean, d2 = s2 - mean, d3 = s3 - mean;
    float vs = d0 * d0 + d1 * d1 + d2 * d2 + d3 * d3;
#pragma unroll
    for (int o = 32; o > 0; o >>= 1) vs += __shfl_xor(vs, o);
    const float rstd = rsqrtf(vs * (1.f / 256.f) + 1e-5f);
    float4 o4;
    o4.x = d0 * rstd * g[lane * 4 + 0] + be[lane * 4 + 0];
    o4.y = d1 * rstd * g[lane * 4 + 1] + be[lane * 4 + 1];
    o4.z = d2 * rstd * g[lane * 4 + 2] + be[lane * 4 + 2];
    o4.w = d3 * rstd * g[lane * 4 + 3] + be[lane * 4 + 3];
    *(float4*)&x[tok * 256 + lane * 4] = o4;
}

// ---------------------------------------------------------------- launch
extern "C" void kernel_launch(void* const* d_in, const int* in_sizes, int n_in,
                              void* d_out, int out_size, void* d_ws, size_t ws_size,
                              hipStream_t stream)
{
    (void)n_in; (void)out_size; (void)ws_size;
    // Input order: setup_inputs() dict order (src/pos interleaved); detect defensively.
    const float* src[4];
    const float* posin[4];
    const bool interleaved = (in_sizes[1] == in_sizes[0]);
    for (int i = 0; i < 4; ++i) {
        if (interleaved) { src[i] = (const float*)d_in[2 * i]; posin[i] = (const float*)d_in[2 * i + 1]; }
        else             { src[i] = (const float*)d_in[i];     posin[i] = (const float*)d_in[4 + i]; }
    }
    const float* lev    = (const float*)d_in[8];
    const float* W_off  = (const float*)d_in[9];
    const float* b_off  = (const float*)d_in[10];
    const float* W_attn = (const float*)d_in[11];
    const float* b_attn = (const float*)d_in[12];
    const float* W_val  = (const float*)d_in[13];
    const float* b_val  = (const float*)d_in[14];
    const float* W_out  = (const float*)d_in[15];
    const float* b_out  = (const float*)d_in[16];
    const float* g1     = (const float*)d_in[17];
    const float* be1    = (const float*)d_in[18];
    const float* W1     = (const float*)d_in[19];
    const float* b1     = (const float*)d_in[20];
    const float* W2     = (const float*)d_in[21];
    const float* b2     = (const float*)d_in[22];
    const float* g2     = (const float*)d_in[23];
    const float* be2    = (const float*)d_in[24];

    float* xbuf = (float*)d_out;                       // x lives in d_out (exact size)
    float* ws   = (float*)d_ws;
    const long SZ256  = NTOK * 256;  // 10,782,720
    const long SZ384  = NTOK * 384;  // 16,174,080
    const long SZ128  = NTOK * 128;  //  5,391,360
    const long SZ1024 = NTOK * 1024; // 43,130,880
    float* posb   = ws;                    // SZ256
    float* region = posb + SZ256;          // SZ1024 (value|off|attn|msda  <->  hidden)
    float* value  = region;
    float* offb   = value + SZ256;
    float* attnb  = offb + SZ384;
    float* msda   = attnb + SZ128;
    float* hidden = region;
    float* tmp    = region + SZ1024;       // SZ256
    float* refb   = tmp + SZ256;           // LEN*3

    pack_kernel<<<(int)((NTOK * 256) / 256), 256, 0, stream>>>(
        src[0], src[1], src[2], src[3], posin[0], posin[1], posin[2], posin[3],
        lev, xbuf, posb);
    ref_kernel<<<(LEN + 63) / 64, 64, 0, stream>>>(refb);

    const int MT = (int)((NTOK + 127) / 128);  // 330
    for (int l = 0; l < 6; ++l) {
        const float* Wv = W_val + (long)l * 256 * 256;
        const float* bv = b_val + (long)l * 256;
        const float* Wo = W_off + (long)l * 256 * 384;
        const float* bo = b_off + (long)l * 384;
        const float* Wa = W_attn + (long)l * 256 * 128;
        const float* ba = b_attn + (long)l * 128;
        const float* Wp = W_out + (long)l * 256 * 256;
        const float* bp = b_out + (long)l * 256;
        const float* W1l = W1 + (long)l * 256 * 1024;
        const float* b1l = b1 + (long)l * 1024;
        const float* W2l = W2 + (long)l * 1024 * 256;
        const float* b2l = b2 + (long)l * 256;

        gemm_kernel<false, false><<<dim3(MT, 2), 256, 0, stream>>>(
            xbuf, nullptr, Wv, bv, value, (int)NTOK, 256, 256);
        gemm_kernel<true, false><<<dim3(MT, 3), 256, 0, stream>>>(
            xbuf, posb, Wo, bo, offb, (int)NTOK, 256, 384);
        gemm_kernel<true, false><<<dim3(MT, 1), 256, 0, stream>>>(
            xbuf, posb, Wa, ba, attnb, (int)NTOK, 256, 128);
        msda_sample_kernel<<<(int)(NTOK * 8 / 8), 256, 0, stream>>>(
            value, offb, attnb, refb, msda);
        gemm_kernel<false, false><<<dim3(MT, 2), 256, 0, stream>>>(
            msda, nullptr, Wp, bp, tmp, (int)NTOK, 256, 256);
        resid_ln_kernel<<<(int)((NTOK + 3) / 4), 256, 0, stream>>>(
            xbuf, tmp, g1 + l * 256, be1 + l * 256);
        gemm_kernel<false, true><<<dim3(MT, 8), 256, 0, stream>>>(
            xbuf, nullptr, W1l, b1l, hidden, (int)NTOK, 256, 1024);
        gemm_kernel<false, false><<<dim3(MT, 2), 256, 0, stream>>>(
            hidden, nullptr, W2l, b2l, tmp, (int)NTOK, 1024, 256);
        resid_ln_kernel<<<(int)((NTOK + 3) / 4), 256, 0, stream>>>(
            xbuf, tmp, g2 + l * 256, be2 + l * 256);
    }
}

// Round 5
// 2820.961 us; speedup vs baseline: 2.7186x; 2.7186x over previous
//
#include <hip/hip_runtime.h>

constexpr int LEN = 5265;
constexpr long NTOK = 8L * LEN;   // 42120

typedef float f32x4 __attribute__((ext_vector_type(4)));
typedef unsigned int u32x4 __attribute__((ext_vector_type(4)));

static __device__ __forceinline__ unsigned short f2bf(float f) {
    unsigned u = __float_as_uint(f);
    unsigned r = (u + 0x7FFFu + ((u >> 16) & 1u)) >> 16;
    return (unsigned short)r;
}
static __device__ __forceinline__ float uasf(unsigned u) { return __uint_as_float(u); }

// ---------------------------------------------------------------- pack
__global__ __launch_bounds__(256) void pack_kernel(
    const float* __restrict__ s0, const float* __restrict__ s1,
    const float* __restrict__ s2, const float* __restrict__ s3,
    const float* __restrict__ p0, const float* __restrict__ p1,
    const float* __restrict__ p2, const float* __restrict__ p3,
    const float* __restrict__ lev,
    float* __restrict__ x, float* __restrict__ pos,
    unsigned short* __restrict__ xbf, unsigned short* __restrict__ qbf)
{
    long t = (long)blockIdx.x * 256 + threadIdx.x;
    if (t >= NTOK * 256) return;
    int c = (int)(t & 255);
    long r = t >> 8;
    int q = (int)(r % LEN);
    int B = (int)(r / LEN);
    int lvl, base, n;
    const float *sp, *pp;
    if (q < 4608)      { lvl = 0; base = 0;    n = 4608; sp = s0; pp = p0; }
    else if (q < 5184) { lvl = 1; base = 4608; n = 576;  sp = s1; pp = p1; }
    else if (q < 5256) { lvl = 2; base = 5184; n = 72;   sp = s2; pp = p2; }
    else               { lvl = 3; base = 5256; n = 9;    sp = s3; pp = p3; }
    int s = q - base;
    long si = ((long)B * 256 + c) * n + s;
    float xv = sp[si];
    float pv = pp[si] + lev[lvl * 256 + c];
    x[t] = xv;
    pos[t] = pv;
    xbf[t] = f2bf(xv);
    qbf[t] = f2bf(xv + pv);
}

// ---------------------------------------------------------------- ref points
__global__ __launch_bounds__(64) void ref_kernel(float* __restrict__ refb)
{
    int q = blockIdx.x * 64 + threadIdx.x;
    if (q >= LEN) return;
    int base, D_, H_, W_;
    if (q < 4608)      { base = 0;    D_ = 8; H_ = 24; W_ = 24; }
    else if (q < 5184) { base = 4608; D_ = 4; H_ = 12; W_ = 12; }
    else if (q < 5256) { base = 5184; D_ = 2; H_ = 6;  W_ = 6;  }
    else               { base = 5256; D_ = 1; H_ = 3;  W_ = 3;  }
    int s = q - base;
    int hw = H_ * W_;
    int z = s / hw; int rem = s - z * hw;
    int y = rem / W_; int xx = rem - y * W_;
    refb[q * 3 + 0] = (xx + 0.5f) / (float)W_;
    refb[q * 3 + 1] = (y + 0.5f) / (float)H_;
    refb[q * 3 + 2] = (z + 0.5f) / (float)D_;
}

// ---------------------------------------------------------------- weight transpose+cvt
// src (L,K,N) f32 -> dst (L,N,K) bf16
__global__ __launch_bounds__(256) void wtrans_kernel(
    const float* __restrict__ src, unsigned short* __restrict__ dst, int K, int N)
{
    __shared__ float t[32][33];
    const int k0 = blockIdx.x * 32, n0 = blockIdx.y * 32;
    const long off = (long)blockIdx.z * K * N;
    src += off; dst += off;
    const int tx = threadIdx.x, ty = threadIdx.y;
    for (int i = ty; i < 32; i += 8)
        t[i][tx] = src[(long)(k0 + i) * N + n0 + tx];
    __syncthreads();
    for (int i = ty; i < 32; i += 8)
        dst[(long)(n0 + i) * K + k0 + tx] = f2bf(t[tx][i]);
}

// ---------------------------------------------------------------- MFMA GEMM
// C[M,N] = A[M,K](bf16) @ Wt[N,K](bf16)^T + bias; 128x128 tile, BK=32,
// 256 thr = 4 waves (2x2), each wave 64x64 = 4x4 frags of 16x16x32.
static __device__ __forceinline__ int swz(int m) { return (m ^ (m >> 2)) & 3; }

template<bool OUTBF, bool RELU>
__global__ __launch_bounds__(256) void mfma_gemm(
    const unsigned short* __restrict__ A, const unsigned short* __restrict__ Wt,
    const float* __restrict__ bias, void* __restrict__ Cv, int M, int K, int N)
{
    __shared__ u32x4 a_l[512];  // 128 rows x 4 slots (16B each)
    __shared__ u32x4 b_l[512];
    const int tid = threadIdx.x;
    const int row0 = blockIdx.x * 128;
    const int col0 = blockIdx.y * 128;
    const int wave = tid >> 6, lane = tid & 63;
    const int wr = wave >> 1, wc = wave & 1;
    const int l15 = lane & 15, l4 = lane >> 4;

    f32x4 acc[4][4];
#pragma unroll
    for (int i = 0; i < 4; ++i)
#pragma unroll
        for (int j = 0; j < 4; ++j) acc[i][j] = (f32x4){0.f, 0.f, 0.f, 0.f};

    const int sm0 = tid >> 2, sk = tid & 3;   // staging: row, 16B-chunk
    const int ar0 = row0 + sm0, ar1 = ar0 + 64;
    const int br0 = col0 + sm0, br1 = br0 + 64;
    const int sw0 = sk ^ swz(sm0);            // swz(sm0+64)==swz(sm0)
    const int slot0 = sm0 * 4 + sw0;
    const int slot1 = (sm0 + 64) * 4 + sw0;

    for (int k0 = 0; k0 < K; k0 += 32) {
        u32x4 av0 = {0, 0, 0, 0}, av1 = {0, 0, 0, 0};
        if (ar0 < M) av0 = *(const u32x4*)&A[(long)ar0 * K + k0 + sk * 8];
        if (ar1 < M) av1 = *(const u32x4*)&A[(long)ar1 * K + k0 + sk * 8];
        const u32x4 bv0 = *(const u32x4*)&Wt[(long)br0 * K + k0 + sk * 8];
        const u32x4 bv1 = *(const u32x4*)&Wt[(long)br1 * K + k0 + sk * 8];
        __syncthreads();
        a_l[slot0] = av0;
        a_l[slot1] = av1;
        b_l[slot0] = bv0;
        b_l[slot1] = bv1;
        __syncthreads();
        u32x4 af[4], bfr[4];
#pragma unroll
        for (int i = 0; i < 4; ++i) {
            const int m = wr * 64 + i * 16 + l15;
            af[i] = a_l[m * 4 + (l4 ^ swz(m))];
            const int n = wc * 64 + i * 16 + l15;
            bfr[i] = b_l[n * 4 + (l4 ^ swz(n))];
        }
#pragma unroll
        for (int i = 0; i < 4; ++i)
#pragma unroll
            for (int j = 0; j < 4; ++j)
                asm volatile("v_mfma_f32_16x16x32_bf16 %0, %1, %2, %0"
                             : "+v"(acc[i][j]) : "v"(af[i]), "v"(bfr[j]));
    }

    float* Cf = (float*)Cv;
    unsigned short* Cb = (unsigned short*)Cv;
    const int cb = col0 + wc * 64;
    float bj[4];
#pragma unroll
    for (int j = 0; j < 4; ++j) bj[j] = bias[cb + j * 16 + l15];
#pragma unroll
    for (int i = 0; i < 4; ++i) {
        const int rb = row0 + wr * 64 + i * 16 + l4 * 4;
#pragma unroll
        for (int r = 0; r < 4; ++r) {
            const int row = rb + r;
            if (row < M) {
#pragma unroll
                for (int j = 0; j < 4; ++j) {
                    const int col = cb + j * 16 + l15;
                    float v = acc[i][j][r] + bj[j];
                    if (RELU) v = fmaxf(v, 0.f);
                    if (OUTBF) Cb[(long)row * N + col] = f2bf(v);
                    else       Cf[(long)row * N + col] = v;
                }
            }
        }
    }
}

// ---------------------------------------------------------------- MSDA sampling
// 32 groups/block (4 tokens), phase1: weights+indices -> LDS; phase2: 8 lanes x
// 4 bf16 channels per group gather-accumulate.
__global__ __launch_bounds__(256) void msda_sample_kernel(
    const unsigned short* __restrict__ value,  // bf16 (tok,256)
    const float* __restrict__ offb,            // (tok,8,16,3)
    const float* __restrict__ attnl,           // (tok,8,16)
    const float* __restrict__ refb,            // (LEN,3)
    unsigned short* __restrict__ outb)         // bf16 (tok,256)  [aliases attnl!]
{
    __shared__ float2 s_wi[32][130];
    const int tid = threadIdx.x;
    const long gid0 = (long)blockIdx.x * 32;

#pragma unroll
    for (int jj = 0; jj < 2; ++jj) {
        const int j = tid + jj * 256;
        const int g = j >> 4, pt = j & 15;
        const long gg = gid0 + g;
        const int h = (int)(gg & 7);
        const long bq = gg >> 3;
        const int q = (int)(bq % LEN);
        const int b = (int)(bq / LEN);

        const float* lg = &attnl[bq * 128 + h * 16];
        float mx = lg[0];
#pragma unroll
        for (int k = 1; k < 16; ++k) mx = fmaxf(mx, lg[k]);
        float den = 0.f;
#pragma unroll
        for (int k = 0; k < 16; ++k) den += __expf(lg[k] - mx);
        const float aw = __expf(lg[pt] - mx) / den;

        const int lvl = pt >> 2;
        int D_, H_, W_, base;
        if (lvl == 0)      { D_ = 8; H_ = 24; W_ = 24; base = 0; }
        else if (lvl == 1) { D_ = 4; H_ = 12; W_ = 12; base = 4608; }
        else if (lvl == 2) { D_ = 2; H_ = 6;  W_ = 6;  base = 5184; }
        else               { D_ = 1; H_ = 3;  W_ = 3;  base = 5256; }
        const float fW = (float)W_, fH = (float)H_, fD = (float)D_;

        const float* op = &offb[(bq * 8 + h) * 48 + pt * 3];
        const float X = (refb[q * 3 + 0] + op[0] / fW) * fW - 0.5f;
        const float Y = (refb[q * 3 + 1] + op[1] / fH) * fH - 0.5f;
        const float Z = (refb[q * 3 + 2] + op[2] / fD) * fD - 0.5f;
        const float x0f = floorf(X), y0f = floorf(Y), z0f = floorf(Z);
        const float fx = X - x0f, fy = Y - y0f, fz = Z - z0f;
        const int x0 = (int)x0f, y0 = (int)y0f, z0 = (int)z0f;
#pragma unroll
        for (int c = 0; c < 8; ++c) {
            const int dx = c & 1, dy = (c >> 1) & 1, dz = c >> 2;
            const int xi = x0 + dx, yi = y0 + dy, zi = z0 + dz;
            float w = (dx ? fx : 1.f - fx) * (dy ? fy : 1.f - fy) * (dz ? fz : 1.f - fz);
            const bool valid = (xi >= 0) && (xi < W_) && (yi >= 0) && (yi < H_) &&
                               (zi >= 0) && (zi < D_);
            const int xc = min(max(xi, 0), W_ - 1);
            const int yc = min(max(yi, 0), H_ - 1);
            const int zc = min(max(zi, 0), D_ - 1);
            const int n = (zc * H_ + yc) * W_ + xc;
            const int idx32 = (int)(((long)b * LEN + base + n) * 256) + h * 32;
            s_wi[g][pt * 8 + c] = make_float2(valid ? w * aw : 0.f,
                                              __int_as_float(idx32));
        }
    }
    __syncthreads();

    const int g = tid >> 3, d4 = tid & 7;
    const long gg = gid0 + g;
    float a0 = 0.f, a1 = 0.f, a2 = 0.f, a3 = 0.f;
#pragma unroll 4
    for (int i = 0; i < 128; ++i) {
        const float2 wi = s_wi[g][i];
        const float w = wi.x;
        const int idx = __float_as_int(wi.y);
        const uint2 v = *(const uint2*)&value[(long)idx + d4 * 4];
        a0 += w * uasf(v.x << 16);
        a1 += w * uasf(v.x & 0xffff0000u);
        a2 += w * uasf(v.y << 16);
        a3 += w * uasf(v.y & 0xffff0000u);
    }
    ushort4 o;
    o.x = f2bf(a0); o.y = f2bf(a1); o.z = f2bf(a2); o.w = f2bf(a3);
    *(ushort4*)&outb[gg * 32 + d4 * 4] = o;
}

// ---------------------------------------------------------------- residual + LN
__global__ __launch_bounds__(256) void resid_ln_kernel(
    float* __restrict__ x, const float* __restrict__ r, const float* __restrict__ pos,
    const float* __restrict__ g, const float* __restrict__ be,
    unsigned short* __restrict__ xbf, unsigned short* __restrict__ qbf)
{
    const long tok = (long)blockIdx.x * 4 + (threadIdx.x >> 6);
    const int lane = threadIdx.x & 63;
    if (tok >= NTOK) return;
    const float4 xv = *(const float4*)&x[tok * 256 + lane * 4];
    const float4 rv = *(const float4*)&r[tok * 256 + lane * 4];
    float s0 = xv.x + rv.x, s1 = xv.y + rv.y, s2 = xv.z + rv.z, s3 = xv.w + rv.w;
    float sum = s0 + s1 + s2 + s3;
#pragma unroll
    for (int o = 32; o > 0; o >>= 1) sum += __shfl_xor(sum, o);
    const float mean = sum * (1.f / 256.f);
    const float d0 = s0 - mean, d1 = s1 - mean, d2 = s2 - mean, d3 = s3 - mean;
    float vs = d0 * d0 + d1 * d1 + d2 * d2 + d3 * d3;
#pragma unroll
    for (int o = 32; o > 0; o >>= 1) vs += __shfl_xor(vs, o);
    const float rstd = rsqrtf(vs * (1.f / 256.f) + 1e-5f);
    float4 o4;
    o4.x = d0 * rstd * g[lane * 4 + 0] + be[lane * 4 + 0];
    o4.y = d1 * rstd * g[lane * 4 + 1] + be[lane * 4 + 1];
    o4.z = d2 * rstd * g[lane * 4 + 2] + be[lane * 4 + 2];
    o4.w = d3 * rstd * g[lane * 4 + 3] + be[lane * 4 + 3];
    *(float4*)&x[tok * 256 + lane * 4] = o4;
    ushort4 xb;
    xb.x = f2bf(o4.x); xb.y = f2bf(o4.y); xb.z = f2bf(o4.z); xb.w = f2bf(o4.w);
    *(ushort4*)&xbf[tok * 256 + lane * 4] = xb;
    const float4 pv = *(const float4*)&pos[tok * 256 + lane * 4];
    ushort4 qb;
    qb.x = f2bf(o4.x + pv.x); qb.y = f2bf(o4.y + pv.y);
    qb.z = f2bf(o4.z + pv.z); qb.w = f2bf(o4.w + pv.w);
    *(ushort4*)&qbf[tok * 256 + lane * 4] = qb;
}

// ---------------------------------------------------------------- launch
extern "C" void kernel_launch(void* const* d_in, const int* in_sizes, int n_in,
                              void* d_out, int out_size, void* d_ws, size_t ws_size,
                              hipStream_t stream)
{
    (void)n_in; (void)out_size; (void)ws_size;
    const float* src[4];
    const float* posin[4];
    const bool interleaved = (in_sizes[1] == in_sizes[0]);
    for (int i = 0; i < 4; ++i) {
        if (interleaved) { src[i] = (const float*)d_in[2 * i]; posin[i] = (const float*)d_in[2 * i + 1]; }
        else             { src[i] = (const float*)d_in[i];     posin[i] = (const float*)d_in[4 + i]; }
    }
    const float* lev    = (const float*)d_in[8];
    const float* W_off  = (const float*)d_in[9];
    const float* b_off  = (const float*)d_in[10];
    const float* W_attn = (const float*)d_in[11];
    const float* b_attn = (const float*)d_in[12];
    const float* W_val  = (const float*)d_in[13];
    const float* b_val  = (const float*)d_in[14];
    const float* W_out  = (const float*)d_in[15];
    const float* b_out  = (const float*)d_in[16];
    const float* g1     = (const float*)d_in[17];
    const float* be1    = (const float*)d_in[18];
    const float* W1     = (const float*)d_in[19];
    const float* b1     = (const float*)d_in[20];
    const float* W2     = (const float*)d_in[21];
    const float* b2     = (const float*)d_in[22];
    const float* g2     = (const float*)d_in[23];
    const float* be2    = (const float*)d_in[24];

    float* xbuf = (float*)d_out;
    char* p = (char*)d_ws;
    float* posb = (float*)p;            p += NTOK * 256 * 4;   // 43.1MB
    float* tmp  = (float*)p;                                    // f32 (tok,256)
    unsigned short* valueb = (unsigned short*)tmp;              // bf16 alias (tok,256)
                                        p += NTOK * 256 * 4;   // 43.1MB
    float* offb  = (float*)p;           p += NTOK * 384 * 4;   // 64.7MB
    float* attnb = (float*)p;                                   // f32 (tok,128)
    unsigned short* msdabf = (unsigned short*)attnb;            // bf16 alias (tok,256)
                                        p += NTOK * 128 * 4;   // 21.6MB
    unsigned short* hidden = (unsigned short*)offb;             // bf16 (tok,1024) aliases offb+attnb
    unsigned short* xbf = (unsigned short*)p;  p += NTOK * 256 * 2;
    unsigned short* qbf = (unsigned short*)p;  p += NTOK * 256 * 2;
    unsigned short* wt_val  = (unsigned short*)p;  p += 6L * 256 * 256 * 2;
    unsigned short* wt_off  = (unsigned short*)p;  p += 6L * 384 * 256 * 2;
    unsigned short* wt_attn = (unsigned short*)p;  p += 6L * 128 * 256 * 2;
    unsigned short* wt_out  = (unsigned short*)p;  p += 6L * 256 * 256 * 2;
    unsigned short* wt_w1   = (unsigned short*)p;  p += 6L * 1024 * 256 * 2;
    unsigned short* wt_w2   = (unsigned short*)p;  p += 6L * 256 * 1024 * 2;
    float* refb = (float*)p;            p += LEN * 3 * 4;

    pack_kernel<<<(int)((NTOK * 256) / 256), 256, 0, stream>>>(
        src[0], src[1], src[2], src[3], posin[0], posin[1], posin[2], posin[3],
        lev, xbuf, posb, xbf, qbf);
    ref_kernel<<<(LEN + 63) / 64, 64, 0, stream>>>(refb);
    dim3 tb(32, 8);
    wtrans_kernel<<<dim3(8, 8, 6),  tb, 0, stream>>>(W_val,  wt_val,  256, 256);
    wtrans_kernel<<<dim3(8, 12, 6), tb, 0, stream>>>(W_off,  wt_off,  256, 384);
    wtrans_kernel<<<dim3(8, 4, 6),  tb, 0, stream>>>(W_attn, wt_attn, 256, 128);
    wtrans_kernel<<<dim3(8, 8, 6),  tb, 0, stream>>>(W_out,  wt_out,  256, 256);
    wtrans_kernel<<<dim3(8, 32, 6), tb, 0, stream>>>(W1,     wt_w1,   256, 1024);
    wtrans_kernel<<<dim3(32, 8, 6), tb, 0, stream>>>(W2,     wt_w2,   1024, 256);

    const int MT = (int)((NTOK + 127) / 128);  // 330
    for (int l = 0; l < 6; ++l) {
        mfma_gemm<true, false><<<dim3(MT, 2), 256, 0, stream>>>(
            xbf, wt_val + (long)l * 65536, b_val + l * 256, valueb, (int)NTOK, 256, 256);
        mfma_gemm<false, false><<<dim3(MT, 3), 256, 0, stream>>>(
            qbf, wt_off + (long)l * 98304, b_off + l * 384, offb, (int)NTOK, 256, 384);
        mfma_gemm<false, false><<<dim3(MT, 1), 256, 0, stream>>>(
            qbf, wt_attn + (long)l * 32768, b_attn + l * 128, attnb, (int)NTOK, 256, 128);
        msda_sample_kernel<<<(int)(NTOK / 4), 256, 0, stream>>>(
            valueb, offb, attnb, refb, msdabf);
        mfma_gemm<false, false><<<dim3(MT, 2), 256, 0, stream>>>(
            msdabf, wt_out + (long)l * 65536, b_out + l * 256, tmp, (int)NTOK, 256, 256);
        resid_ln_kernel<<<(int)((NTOK + 3) / 4), 256, 0, stream>>>(
            xbuf, tmp, posb, g1 + l * 256, be1 + l * 256, xbf, qbf);
        mfma_gemm<true, true><<<dim3(MT, 8), 256, 0, stream>>>(
            xbf, wt_w1 + (long)l * 262144, b1 + l * 1024, hidden, (int)NTOK, 256, 1024);
        mfma_gemm<false, false><<<dim3(MT, 2), 256, 0, stream>>>(
            hidden, wt_w2 + (long)l * 262144, b2 + l * 256, tmp, (int)NTOK, 1024, 256);
        resid_ln_kernel<<<(int)((NTOK + 3) / 4), 256, 0, stream>>>(
            xbuf, tmp, posb, g2 + l * 256, be2 + l * 256, xbf, qbf);
    }
}

// Round 7
// 2593.260 us; speedup vs baseline: 2.9573x; 1.0878x over previous
//
#include <hip/hip_runtime.h>
#include <hip/hip_fp16.h>

constexpr int LEN = 5265;
constexpr long NTOK = 8L * LEN;   // 42120

typedef float f32x4 __attribute__((ext_vector_type(4)));
typedef unsigned int u32x4 __attribute__((ext_vector_type(4)));

static __device__ __forceinline__ unsigned short f2bf(float f) {
    unsigned u = __float_as_uint(f);
    unsigned r = (u + 0x7FFFu + ((u >> 16) & 1u)) >> 16;
    return (unsigned short)r;
}
static __device__ __forceinline__ float uasf(unsigned u) { return __uint_as_float(u); }

#if __has_builtin(__builtin_amdgcn_global_load_lds)
#define HAS_GLL 1
static __device__ __forceinline__ void gll16(const void* g, void* l) {
    __builtin_amdgcn_global_load_lds(
        (const __attribute__((address_space(1))) void*)g,
        (__attribute__((address_space(3))) void*)l, 16, 0, 0);
}
#else
#define HAS_GLL 0
#endif

// ---------------------------------------------------------------- pack
__global__ __launch_bounds__(256) void pack_kernel(
    const float* __restrict__ s0, const float* __restrict__ s1,
    const float* __restrict__ s2, const float* __restrict__ s3,
    const float* __restrict__ p0, const float* __restrict__ p1,
    const float* __restrict__ p2, const float* __restrict__ p3,
    const float* __restrict__ lev,
    float* __restrict__ x, float* __restrict__ pos,
    unsigned short* __restrict__ xbf, unsigned short* __restrict__ qbf)
{
    long t = (long)blockIdx.x * 256 + threadIdx.x;
    if (t >= NTOK * 256) return;
    int c = (int)(t & 255);
    long r = t >> 8;
    int q = (int)(r % LEN);
    int B = (int)(r / LEN);
    int lvl, base, n;
    const float *sp, *pp;
    if (q < 4608)      { lvl = 0; base = 0;    n = 4608; sp = s0; pp = p0; }
    else if (q < 5184) { lvl = 1; base = 4608; n = 576;  sp = s1; pp = p1; }
    else if (q < 5256) { lvl = 2; base = 5184; n = 72;   sp = s2; pp = p2; }
    else               { lvl = 3; base = 5256; n = 9;    sp = s3; pp = p3; }
    int s = q - base;
    long si = ((long)B * 256 + c) * n + s;
    float xv = sp[si];
    float pv = pp[si] + lev[lvl * 256 + c];
    x[t] = xv;
    pos[t] = pv;
    xbf[t] = f2bf(xv);
    qbf[t] = f2bf(xv + pv);
}

// ---------------------------------------------------------------- ref points
__global__ __launch_bounds__(64) void ref_kernel(float* __restrict__ refb)
{
    int q = blockIdx.x * 64 + threadIdx.x;
    if (q >= LEN) return;
    int base, D_, H_, W_;
    if (q < 4608)      { base = 0;    D_ = 8; H_ = 24; W_ = 24; }
    else if (q < 5184) { base = 4608; D_ = 4; H_ = 12; W_ = 12; }
    else if (q < 5256) { base = 5184; D_ = 2; H_ = 6;  W_ = 6;  }
    else               { base = 5256; D_ = 1; H_ = 3;  W_ = 3;  }
    int s = q - base;
    int hw = H_ * W_;
    int z = s / hw; int rem = s - z * hw;
    int y = rem / W_; int xx = rem - y * W_;
    refb[q * 3 + 0] = (xx + 0.5f) / (float)W_;
    refb[q * 3 + 1] = (y + 0.5f) / (float)H_;
    refb[q * 3 + 2] = (z + 0.5f) / (float)D_;
}

// ---------------------------------------------------------------- weight transpose+cvt
// src (L,K,N) f32 -> dst (L as dstLS, N, K) bf16
__global__ __launch_bounds__(256) void wtrans_kernel(
    const float* __restrict__ src, unsigned short* __restrict__ dst,
    int K, int N, long dstLS)
{
    __shared__ float t[32][33];
    const int k0 = blockIdx.x * 32, n0 = blockIdx.y * 32;
    src += (long)blockIdx.z * K * N;
    dst += (long)blockIdx.z * dstLS;
    const int tx = threadIdx.x, ty = threadIdx.y;
    for (int i = ty; i < 32; i += 8)
        t[i][tx] = src[(long)(k0 + i) * N + n0 + tx];
    __syncthreads();
    for (int i = ty; i < 32; i += 8)
        dst[(long)(n0 + i) * K + k0 + tx] = f2bf(t[tx][i]);
}

// ---------------------------------------------------------------- MFMA GEMM
// C[M,N] = A[M,K](bf16) @ Wt[N,K](bf16)^T + bias; 128x128 tile, BK=32,
// 256 thr = 4 waves (2x2), each wave 64x64 = 4x4 frags of 16x16x32.
// Staging: global_load_lds w=16, linear LDS dest, pre-swizzled global source.
static __device__ __forceinline__ int swz(int m) { return (m ^ (m >> 2)) & 3; }

template<bool OUTBF, bool RELU>
__global__ __launch_bounds__(256) void mfma_gemm(
    const unsigned short* __restrict__ A, const unsigned short* __restrict__ Wt,
    const float* __restrict__ bias, const float* __restrict__ bias2, int nb0,
    void* __restrict__ Cv, int M, int K, int N)
{
    __shared__ u32x4 a_l[512];  // slot = row*4 + s; slot s holds chunk s^swz(row)
    __shared__ u32x4 b_l[512];
    const int tid = threadIdx.x;
    const int row0 = blockIdx.x * 128;
    const int col0 = blockIdx.y * 128;
    const int wave = tid >> 6, lane = tid & 63;
    const int wr = wave >> 1, wc = wave & 1;
    const int l15 = lane & 15, l4 = lane >> 4;

    f32x4 acc[4][4];
#pragma unroll
    for (int i = 0; i < 4; ++i)
#pragma unroll
        for (int j = 0; j < 4; ++j) acc[i][j] = (f32x4){0.f, 0.f, 0.f, 0.f};

    const int sm0 = tid >> 2, sk = tid & 3;
    const int swk = (sk ^ swz(sm0)) * 8;      // swz(sm0+64)==swz(sm0)
    const int arA0 = min(row0 + sm0, M - 1);  // clamped rows only affect C rows >=M
    const int arA1 = min(row0 + sm0 + 64, M - 1);
    const unsigned short* gA0 = A  + (long)arA0 * K + swk;
    const unsigned short* gA1 = A  + (long)arA1 * K + swk;
    const unsigned short* gB0 = Wt + (long)(col0 + sm0) * K + swk;
    const unsigned short* gB1 = Wt + (long)(col0 + sm0 + 64) * K + swk;

    for (int k0 = 0; k0 < K; k0 += 32) {
        __syncthreads();                       // all waves done reading prev tile
#if HAS_GLL
        gll16(gA0 + k0, &a_l[wave * 64]);
        gll16(gA1 + k0, &a_l[256 + wave * 64]);
        gll16(gB0 + k0, &b_l[wave * 64]);
        gll16(gB1 + k0, &b_l[256 + wave * 64]);
#else
        a_l[tid]       = *(const u32x4*)(gA0 + k0);
        a_l[256 + tid] = *(const u32x4*)(gA1 + k0);
        b_l[tid]       = *(const u32x4*)(gB0 + k0);
        b_l[256 + tid] = *(const u32x4*)(gB1 + k0);
#endif
        __syncthreads();                       // drains vmcnt -> LDS filled
        u32x4 af[4], bfr[4];
#pragma unroll
        for (int i = 0; i < 4; ++i) {
            const int m = wr * 64 + i * 16 + l15;
            af[i] = a_l[m * 4 + (l4 ^ swz(m))];
            const int n = wc * 64 + i * 16 + l15;
            bfr[i] = b_l[n * 4 + (l4 ^ swz(n))];
        }
#pragma unroll
        for (int i = 0; i < 4; ++i)
#pragma unroll
            for (int j = 0; j < 4; ++j)
                asm volatile("v_mfma_f32_16x16x32_bf16 %0, %1, %2, %0"
                             : "+v"(acc[i][j]) : "v"(af[i]), "v"(bfr[j]));
    }

    float* Cf = (float*)Cv;
    unsigned short* Cb = (unsigned short*)Cv;
    const int cb = col0 + wc * 64;
    float bj[4];
#pragma unroll
    for (int j = 0; j < 4; ++j) {
        const int col = cb + j * 16 + l15;
        bj[j] = (col < nb0) ? bias[col] : bias2[col - nb0];
    }
#pragma unroll
    for (int i = 0; i < 4; ++i) {
        const int rb = row0 + wr * 64 + i * 16 + l4 * 4;
#pragma unroll
        for (int r = 0; r < 4; ++r) {
            const int row = rb + r;
            if (row < M) {
#pragma unroll
                for (int j = 0; j < 4; ++j) {
                    const int col = cb + j * 16 + l15;
                    float v = acc[i][j][r] + bj[j];
                    if (RELU) v = fmaxf(v, 0.f);
                    if (OUTBF) Cb[(long)row * N + col] = f2bf(v);
                    else       Cf[(long)row * N + col] = v;
                }
            }
        }
    }
}

// ---------------------------------------------------------------- MSDA sampling
// 32 groups/block (4 tokens). Phase1: (f16 w | u16 tokidx) -> LDS [g][c][pt]
// (2-way conflict = free). Phase2: 8 lanes x 4 bf16 ch per group gather.
__global__ __launch_bounds__(256) void msda_sample_kernel(
    const unsigned short* __restrict__ value,  // bf16 (tok,256)
    const float* __restrict__ obuf,            // f32 (tok,512): off[0:384], logits[384:512]
    const float* __restrict__ refb,            // (LEN,3)
    unsigned short* __restrict__ outb)         // bf16 (tok,256)
{
    __shared__ unsigned s_wi[32][8][17];       // 17408 B -> 8 blocks/CU
    const int tid = threadIdx.x;
    const long gid0 = (long)blockIdx.x * 32;

#pragma unroll
    for (int jj = 0; jj < 2; ++jj) {
        const int j = tid + jj * 256;          // 0..511 = 32 groups x 16 pts
        const int g = j >> 4, pt = j & 15;
        const long gg = gid0 + g;
        const int h = (int)(gg & 7);
        const long tok = gg >> 3;
        const int q = (int)(tok % LEN);
        const int b = (int)(tok / LEN);

        const float* lg = &obuf[tok * 512 + 384 + h * 16];
        float mx = lg[0];
#pragma unroll
        for (int k = 1; k < 16; ++k) mx = fmaxf(mx, lg[k]);
        float den = 0.f;
#pragma unroll
        for (int k = 0; k < 16; ++k) den += __expf(lg[k] - mx);
        const float aw = __expf(lg[pt] - mx) / den;

        const int lvl = pt >> 2;
        int D_, H_, W_, base;
        if (lvl == 0)      { D_ = 8; H_ = 24; W_ = 24; base = 0; }
        else if (lvl == 1) { D_ = 4; H_ = 12; W_ = 12; base = 4608; }
        else if (lvl == 2) { D_ = 2; H_ = 6;  W_ = 6;  base = 5184; }
        else               { D_ = 1; H_ = 3;  W_ = 3;  base = 5256; }
        const float fW = (float)W_, fH = (float)H_, fD = (float)D_;

        const float* op = &obuf[tok * 512 + h * 48 + pt * 3];
        const float X = (refb[q * 3 + 0] + op[0] / fW) * fW - 0.5f;
        const float Y = (refb[q * 3 + 1] + op[1] / fH) * fH - 0.5f;
        const float Z = (refb[q * 3 + 2] + op[2] / fD) * fD - 0.5f;
        const float x0f = floorf(X), y0f = floorf(Y), z0f = floorf(Z);
        const float fx = X - x0f, fy = Y - y0f, fz = Z - z0f;
        const int x0 = (int)x0f, y0 = (int)y0f, z0 = (int)z0f;
#pragma unroll
        for (int c = 0; c < 8; ++c) {
            const int dx = c & 1, dy = (c >> 1) & 1, dz = c >> 2;
            const int xi = x0 + dx, yi = y0 + dy, zi = z0 + dz;
            float w = (dx ? fx : 1.f - fx) * (dy ? fy : 1.f - fy) * (dz ? fz : 1.f - fz);
            const bool valid = (xi >= 0) && (xi < W_) && (yi >= 0) && (yi < H_) &&
                               (zi >= 0) && (zi < D_);
            const int xc = min(max(xi, 0), W_ - 1);
            const int yc = min(max(yi, 0), H_ - 1);
            const int zc = min(max(zi, 0), D_ - 1);
            const int n = (zc * H_ + yc) * W_ + xc;
            const unsigned short ti = (unsigned short)(b * LEN + base + n);  // < 42120
            const unsigned short hw =
                __half_as_ushort(__float2half_rn(valid ? w * aw : 0.f));
            s_wi[g][c][pt] = ((unsigned)ti << 16) | (unsigned)hw;
        }
    }
    __syncthreads();

    const int g = tid >> 3, d4 = tid & 7;
    const long gg = gid0 + g;
    const int h = (int)(gg & 7);
    const char* vbase = (const char*)value + h * 64 + d4 * 8;
    const unsigned* sp = &s_wi[g][0][0];
    float a0 = 0.f, a1 = 0.f, a2 = 0.f, a3 = 0.f;
#pragma unroll
    for (int c = 0; c < 8; ++c) {
#pragma unroll
        for (int pt = 0; pt < 16; ++pt) {
            const unsigned word = sp[c * 17 + pt];
            const float w = __half2float(__ushort_as_half((unsigned short)word));
            const uint2 v = *(const uint2*)(vbase + ((word >> 16) << 9));
            a0 += w * uasf(v.x << 16);
            a1 += w * uasf(v.x & 0xffff0000u);
            a2 += w * uasf(v.y << 16);
            a3 += w * uasf(v.y & 0xffff0000u);
        }
    }
    ushort4 o;
    o.x = f2bf(a0); o.y = f2bf(a1); o.z = f2bf(a2); o.w = f2bf(a3);
    *(ushort4*)&outb[gg * 32 + d4 * 4] = o;
}

// ---------------------------------------------------------------- residual + LN
template<bool NEEDQ>
__global__ __launch_bounds__(256) void resid_ln_kernel(
    float* __restrict__ x, const float* __restrict__ r, const float* __restrict__ pos,
    const float* __restrict__ g, const float* __restrict__ be,
    unsigned short* __restrict__ xbf, unsigned short* __restrict__ qbf)
{
    const long tok = (long)blockIdx.x * 4 + (threadIdx.x >> 6);
    const int lane = threadIdx.x & 63;
    if (tok >= NTOK) return;
    const float4 xv = *(const float4*)&x[tok * 256 + lane * 4];
    const float4 rv = *(const float4*)&r[tok * 256 + lane * 4];
    float s0 = xv.x + rv.x, s1 = xv.y + rv.y, s2 = xv.z + rv.z, s3 = xv.w + rv.w;
    float sum = s0 + s1 + s2 + s3;
#pragma unroll
    for (int o = 32; o > 0; o >>= 1) sum += __shfl_xor(sum, o);
    const float mean = sum * (1.f / 256.f);
    const float d0 = s0 - mean, d1 = s1 - mean, d2 = s2 - mean, d3 = s3 - mean;
    float vs = d0 * d0 + d1 * d1 + d2 * d2 + d3 * d3;
#pragma unroll
    for (int o = 32; o > 0; o >>= 1) vs += __shfl_xor(vs, o);
    const float rstd = rsqrtf(vs * (1.f / 256.f) + 1e-5f);
    float4 o4;
    o4.x = d0 * rstd * g[lane * 4 + 0] + be[lane * 4 + 0];
    o4.y = d1 * rstd * g[lane * 4 + 1] + be[lane * 4 + 1];
    o4.z = d2 * rstd * g[lane * 4 + 2] + be[lane * 4 + 2];
    o4.w = d3 * rstd * g[lane * 4 + 3] + be[lane * 4 + 3];
    *(float4*)&x[tok * 256 + lane * 4] = o4;
    ushort4 xb;
    xb.x = f2bf(o4.x); xb.y = f2bf(o4.y); xb.z = f2bf(o4.z); xb.w = f2bf(o4.w);
    *(ushort4*)&xbf[tok * 256 + lane * 4] = xb;
    if (NEEDQ) {
        const float4 pv = *(const float4*)&pos[tok * 256 + lane * 4];
        ushort4 qb;
        qb.x = f2bf(o4.x + pv.x); qb.y = f2bf(o4.y + pv.y);
        qb.z = f2bf(o4.z + pv.z); qb.w = f2bf(o4.w + pv.w);
        *(ushort4*)&qbf[tok * 256 + lane * 4] = qb;
    }
}

// ---------------------------------------------------------------- launch
extern "C" void kernel_launch(void* const* d_in, const int* in_sizes, int n_in,
                              void* d_out, int out_size, void* d_ws, size_t ws_size,
                              hipStream_t stream)
{
    (void)n_in; (void)out_size; (void)ws_size;
    const float* src[4];
    const float* posin[4];
    const bool interleaved = (in_sizes[1] == in_sizes[0]);
    for (int i = 0; i < 4; ++i) {
        if (interleaved) { src[i] = (const float*)d_in[2 * i]; posin[i] = (const float*)d_in[2 * i + 1]; }
        else             { src[i] = (const float*)d_in[i];     posin[i] = (const float*)d_in[4 + i]; }
    }
    const float* lev    = (const float*)d_in[8];
    const float* W_off  = (const float*)d_in[9];
    const float* b_off  = (const float*)d_in[10];
    const float* W_attn = (const float*)d_in[11];
    const float* b_attn = (const float*)d_in[12];
    const float* W_val  = (const float*)d_in[13];
    const float* b_val  = (const float*)d_in[14];
    const float* W_out  = (const float*)d_in[15];
    const float* b_out  = (const float*)d_in[16];
    const float* g1     = (const float*)d_in[17];
    const float* be1    = (const float*)d_in[18];
    const float* W1     = (const float*)d_in[19];
    const float* b1     = (const float*)d_in[20];
    const float* W2     = (const float*)d_in[21];
    const float* b2     = (const float*)d_in[22];
    const float* g2     = (const float*)d_in[23];
    const float* be2    = (const float*)d_in[24];

    float* xbuf = (float*)d_out;
    char* p = (char*)d_ws;
    float* posb = (float*)p;            p += NTOK * 256 * 4;   // 43.1MB
    float* tmp  = (float*)p;                                    // f32 (tok,256)
    unsigned short* valueb = (unsigned short*)tmp;              // bf16 alias (tok,256)
                                        p += NTOK * 256 * 4;   // 43.1MB
    float* obuf = (float*)p;                                    // f32 (tok,512) off|logits
    unsigned short* hidden = (unsigned short*)obuf;             // bf16 alias (tok,1024)
                                        p += NTOK * 512 * 4;   // 86.3MB
    unsigned short* msdabf = (unsigned short*)p;  p += NTOK * 256 * 2;
    unsigned short* xbf    = (unsigned short*)p;  p += NTOK * 256 * 2;
    unsigned short* qbf    = (unsigned short*)p;  p += NTOK * 256 * 2;
    unsigned short* wt_val = (unsigned short*)p;  p += 6L * 256 * 256 * 2;
    unsigned short* wt_oa  = (unsigned short*)p;  p += 6L * 512 * 256 * 2;
    unsigned short* wt_out = (unsigned short*)p;  p += 6L * 256 * 256 * 2;
    unsigned short* wt_w1  = (unsigned short*)p;  p += 6L * 1024 * 256 * 2;
    unsigned short* wt_w2  = (unsigned short*)p;  p += 6L * 256 * 1024 * 2;
    float* refb = (float*)p;            p += LEN * 3 * 4;

    pack_kernel<<<(int)((NTOK * 256) / 256), 256, 0, stream>>>(
        src[0], src[1], src[2], src[3], posin[0], posin[1], posin[2], posin[3],
        lev, xbuf, posb, xbf, qbf);
    ref_kernel<<<(LEN + 63) / 64, 64, 0, stream>>>(refb);
    dim3 tb(32, 8);
    wtrans_kernel<<<dim3(8, 8, 6),  tb, 0, stream>>>(W_val,  wt_val, 256, 256,  65536);
    wtrans_kernel<<<dim3(8, 12, 6), tb, 0, stream>>>(W_off,  wt_oa,  256, 384,  131072);
    wtrans_kernel<<<dim3(8, 4, 6),  tb, 0, stream>>>(W_attn, wt_oa + 384 * 256, 256, 128, 131072);
    wtrans_kernel<<<dim3(8, 8, 6),  tb, 0, stream>>>(W_out,  wt_out, 256, 256,  65536);
    wtrans_kernel<<<dim3(8, 32, 6), tb, 0, stream>>>(W1,     wt_w1,  256, 1024, 262144);
    wtrans_kernel<<<dim3(32, 8, 6), tb, 0, stream>>>(W2,     wt_w2,  1024, 256, 262144);

    const int MT = (int)((NTOK + 127) / 128);  // 330
    const int BIG = 1 << 30;
    for (int l = 0; l < 6; ++l) {
        mfma_gemm<true, false><<<dim3(MT, 2), 256, 0, stream>>>(
            xbf, wt_val + (long)l * 65536, b_val + l * 256, b_val + l * 256, BIG,
            valueb, (int)NTOK, 256, 256);
        mfma_gemm<false, false><<<dim3(MT, 4), 256, 0, stream>>>(
            qbf, wt_oa + (long)l * 131072, b_off + l * 384, b_attn + l * 128, 384,
            obuf, (int)NTOK, 256, 512);
        msda_sample_kernel<<<(int)(NTOK / 4), 256, 0, stream>>>(
            valueb, obuf, refb, msdabf);
        mfma_gemm<false, false><<<dim3(MT, 2), 256, 0, stream>>>(
            msdabf, wt_out + (long)l * 65536, b_out + l * 256, b_out + l * 256, BIG,
            tmp, (int)NTOK, 256, 256);
        resid_ln_kernel<false><<<(int)((NTOK + 3) / 4), 256, 0, stream>>>(
            xbuf, tmp, posb, g1 + l * 256, be1 + l * 256, xbf, qbf);
        mfma_gemm<true, true><<<dim3(MT, 8), 256, 0, stream>>>(
            xbf, wt_w1 + (long)l * 262144, b1 + l * 1024, b1 + l * 1024, BIG,
            hidden, (int)NTOK, 256, 1024);
        mfma_gemm<false, false><<<dim3(MT, 2), 256, 0, stream>>>(
            hidden, wt_w2 + (long)l * 262144, b2 + l * 256, b2 + l * 256, BIG,
            tmp, (int)NTOK, 1024, 256);
        resid_ln_kernel<true><<<(int)((NTOK + 3) / 4), 256, 0, stream>>>(
            xbuf, tmp, posb, g2 + l * 256, be2 + l * 256, xbf, qbf);
    }
}